// Round 4
// baseline (2433.829 us; speedup 1.0000x reference)
//
#include <hip/hip_runtime.h>

#define NN 512
#define NM1 511
#define PCT(r, j) pcT[(r) * 13 + (j)]

// One block per matrix (1024 blocks). Blocked LU, panel r=8, implicit partial
// pivoting. Thread tile: rows {L,L+64,L+128,L+192} x cols [16w,16w+16) in regs
// (at[4][16]). Row-threads = tid>=768 (r = tid-768) run the panel column-steps
// with the panel row cached in regs (pcrow[8]). One barrier per column-step;
// rank-8 trailing update amortizes LDS broadcasts and barriers.
//
// amdgpu_waves_per_eu(4,4): r3 post-mortem — with LDS=42.5KB two blocks/CU
// fit, allocator targeted 8 waves/EU (64 VGPR) and spilled at[4][16] to
// scratch (3.4GB WRITE_SIZE/dispatch). Clamp occupancy target to 4 waves/EU
// (128 VGPR budget) AND pad LDS past 80KiB so only 1 block/CU fits.
__global__ __attribute__((amdgpu_waves_per_eu(4, 4))) __launch_bounds__(1024)
void det_lu_kernel(
    const float* __restrict__ x,
    const float* __restrict__ F,
    float* __restrict__ out) {
  __shared__ __align__(16) float pcT[256 * 13];   // panel cols, row-major pad 13
  __shared__ __align__(16) float lbuf[8 * 256];   // multipliers per step
  __shared__ __align__(16) float Ubuf[8 * 260];   // final pivot rows (pad 260)
  __shared__ __align__(16) float araw[8 * 260];   // raw pivot rows
  __shared__ float livef[256];
  __shared__ int   perm[256];
  __shared__ int   upbuf[256];
  __shared__ int   dnbuf[256];
  __shared__ int   wavecnt[8];
  __shared__ int   totinv;
  __shared__ float ldspad[10000];   // occupancy limiter: LDS > 80KiB -> 1 blk/CU

  const int tid = threadIdx.x;
  const int L   = tid & 63;       // lane
  const int w   = tid >> 6;       // wave

  const float* xrow = x + (size_t)blockIdx.x * NN;

  // keep ldspad referenced (opaque never-true condition; costs one branch)
  if ((int)blockIdx.x < 0) ((volatile float*)ldspad)[tid] = 1.0f;

  // ---- rank the +/-1 pattern: up = x>0 positions, dn = x<=0 positions
  bool pos = false;
  unsigned long long mask = 0;
  if (tid < NN) {
    float xv = xrow[tid];
    pos = xv > 0.0f;
    mask = __ballot(pos);
    if (L == 0) wavecnt[w] = __popcll(mask);
  }
  if (tid == 0) totinv = 0;
  if (tid < 256) livef[tid] = 1.0f;
  __syncthreads();
  if (tid < NN) {
    int base = 0;
    for (int i = 0; i < w; i++) base += wavecnt[i];
    int pbelow = __popcll(mask & ((1ull << L) - 1ull));
    if (pos) upbuf[base + pbelow] = tid;
    else     dnbuf[(64 * w - base) + (L - pbelow)] = tid;
  }
  __syncthreads();

  // ---- gather submatrix tile into registers: at[k][m] = sub[L+64k][16w+m]
  float at[4][16];
  {
    int cg[16];
#pragma unroll
    for (int m = 0; m < 16; m++) cg[m] = dnbuf[16 * w + m];
#pragma unroll
    for (int k = 0; k < 4; k++) {
      int rg = upbuf[L + 64 * k];
#pragma unroll
      for (int m = 0; m < 16; m++) {
        int c = cg[m];
        at[k][m] = (c == rg) ? 0.0f : F[(size_t)rg * NM1 + c - (c > rg ? 1 : 0)];
      }
    }
  }

  // ---- seed panel 0: wave 0 writes pcT[row][0..7] = at[k][0..7]
  if (w == 0) {
#pragma unroll
    for (int k = 0; k < 4; k++) {
      int rho = L + 64 * k;
#pragma unroll
      for (int j = 0; j < 8; j++) PCT(rho, j) = at[k][j];
    }
  }
  double det = 1.0;
  bool mylive = true;          // row-thread's own-row liveness (tid>=768)
  __syncthreads();

  // ---- panel loop
  for (int P = 0; P < 32; P++) {
    // row-threads cache their panel row in registers
    float pcrow[8];
    if (tid >= 768) {
      const int rr = tid - 768;
#pragma unroll
      for (int j = 0; j < 8; j++) pcrow[j] = PCT(rr, j);
    }

    int parr[8];
    // -------- 8 column-steps, ONE barrier each --------
#pragma unroll
    for (int s = 0; s < 8; s++) {
      // search: all threads, redundant; exclusion via register pivot history
      unsigned key = 0u;
#pragma unroll
      for (int k = 0; k < 4; k++) {
        int rho = L + 64 * k;
        float v = PCT(rho, s);
        bool excl = false;
#pragma unroll
        for (int q = 0; q < s; q++) excl |= (rho == parr[q]);
        unsigned b = __float_as_uint(fabsf(v)) & 0xFFFFFF00u;
        unsigned kq = excl ? 0u : (b | (unsigned)rho);
        key = key > kq ? key : kq;
      }
#pragma unroll
      for (int off = 32; off; off >>= 1) {
        unsigned o = (unsigned)__shfl_xor((int)key, off);
        key = key > o ? key : o;
      }
      const int p = (int)(key & 255u);
      parr[s] = p;
      const float piv = PCT(p, s);   // nobody writes col s this step
      det *= (double)piv;

      if (tid >= 768) {              // row-thread work
        const int rr = tid - 768;
        const float invp = 1.0f / piv;
        float l = (mylive && rr != p) ? pcrow[s] * invp : 0.0f;
        lbuf[s * 256 + rr] = l;
        if (rr == p) { mylive = false; livef[rr] = 0.0f; perm[P * 8 + s] = p; }
#pragma unroll
        for (int j = s + 1; j < 8; j++) {
          float uj = PCT(p, j);      // pivot row: benign same-value rewrite
          pcrow[j] = fmaf(-l, uj, pcrow[j]);
          PCT(rr, j) = pcrow[j];
        }
      }
      // raw pivot-row stash for the U-solve (live-col waves only)
      if ((2 * w + 1 > P) && L == (p & 63)) {
        const int kp = p >> 6;
#pragma unroll
        for (int kk = 0; kk < 4; kk++) if (kk == kp) {
#pragma unroll
          for (int q = 0; q < 4; q++)
            *reinterpret_cast<float4*>(&araw[s * 260 + 16 * w + 4 * q]) =
                make_float4(at[kk][4*q], at[kk][4*q+1], at[kk][4*q+2], at[kk][4*q+3]);
        }
      }
      __syncthreads();
    }

    // -------- U-solve: U[t][j] = araw[t][j] - sum_{s<t} l_s[p_t]*U[s][j]
    if (tid < 256) {
      const int j = tid;
      float u[8];
#pragma unroll
      for (int t = 0; t < 8; t++) {
        int pt = perm[P * 8 + t];
        float acc = araw[t * 260 + j];
#pragma unroll
        for (int s2 = 0; s2 < t; s2++) acc = fmaf(-lbuf[s2 * 256 + pt], u[s2], acc);
        u[t] = acc;
        Ubuf[t * 260 + j] = acc;
      }
    }
    __syncthreads();

    // -------- rank-8 trailing update + seed next panel --------
    if (2 * w + 1 > P) {
#pragma unroll
      for (int t = 0; t < 8; t++) {
        float lk[4];
#pragma unroll
        for (int k = 0; k < 4; k++) lk[k] = lbuf[t * 256 + L + 64 * k];
#pragma unroll
        for (int q = 0; q < 4; q++) {
          const float4 u4 =
              *reinterpret_cast<const float4*>(&Ubuf[t * 260 + 16 * w + 4 * q]);
#pragma unroll
          for (int k = 0; k < 4; k++) {
            at[k][4*q+0] = fmaf(-lk[k], u4.x, at[k][4*q+0]);
            at[k][4*q+1] = fmaf(-lk[k], u4.y, at[k][4*q+1]);
            at[k][4*q+2] = fmaf(-lk[k], u4.z, at[k][4*q+2]);
            at[k][4*q+3] = fmaf(-lk[k], u4.w, at[k][4*q+3]);
          }
        }
      }
    }
    {
      const int wstar = (P + 1) >> 1, h = (P + 1) & 1;
      if (P < 31 && w == wstar) {
#pragma unroll
        for (int k = 0; k < 4; k++) {
          int rho = L + 64 * k;
          float lv = livef[rho];
#pragma unroll
          for (int hh = 0; hh < 2; hh++) if (hh == h) {
#pragma unroll
            for (int j = 0; j < 8; j++) PCT(rho, j) = at[k][8 * hh + j] * lv;
          }
        }
      }
    }
    __syncthreads();
  }

  // ---- permutation parity via parallel inversion count (verified in r2)
  int myinv = 0;
  {
    const int i0 = tid & 255;
    const int cbase = (tid >> 8) * 64;
    const int pi = perm[i0];
#pragma unroll 8
    for (int j = 0; j < 64; j++) {
      int jj = cbase + j;
      if (jj > i0 && perm[jj] < pi) myinv++;
    }
  }
#pragma unroll
  for (int off = 32; off; off >>= 1) myinv += __shfl_xor(myinv, off);
  if (L == 0) atomicAdd(&totinv, myinv);
  __syncthreads();
  if (tid == 0) out[blockIdx.x] = (float)((totinv & 1) ? -det : det);
}

extern "C" void kernel_launch(void* const* d_in, const int* in_sizes, int n_in,
                              void* d_out, int out_size, void* d_ws, size_t ws_size,
                              hipStream_t stream) {
  const float* x = (const float*)d_in[0];   // (1024, 512) fp32
  const float* F = (const float*)d_in[1];   // (512*512-512,) fp32
  float* out = (float*)d_out;               // (1024,) fp32
  const int B = out_size;                   // 1024
  hipLaunchKernelGGL(det_lu_kernel, dim3(B), dim3(1024), 0, stream, x, F, out);
}

// Round 5
// 2430.456 us; speedup vs baseline: 1.0014x; 1.0014x over previous
//
#include <hip/hip_runtime.h>

#define NN 512
#define NM1 511
#define PCT(r, j) pcT[(r) * 13 + (j)]

typedef float f16v __attribute__((ext_vector_type(16)));
typedef float f8v  __attribute__((ext_vector_type(8)));
typedef int   i16v __attribute__((ext_vector_type(16)));
typedef int   i8v  __attribute__((ext_vector_type(8)));

// One block per matrix (1024 blocks). Blocked LU, panel r=8, implicit partial
// pivoting. Thread tile: rows {L,L+64,L+128,L+192} x cols [16w,16w+16) held in
// FOUR NAMED ext_vector registers at0..at3 (r3/r4 post-mortem: the 2-D alloca
// at[4][16] was never promoted out of scratch -> 3.9GB spill traffic; vectors
// are SSA, cannot be demoted). Row-threads tid>=768 run the panel column-steps.
__global__ __attribute__((amdgpu_waves_per_eu(4, 4))) __launch_bounds__(1024)
void det_lu_kernel(
    const float* __restrict__ x,
    const float* __restrict__ F,
    float* __restrict__ out) {
  __shared__ __align__(16) float pcT[256 * 13];   // panel cols, row-major pad 13
  __shared__ __align__(16) float lbuf[8 * 256];   // multipliers per step
  __shared__ __align__(16) float Ubuf[8 * 260];   // final pivot rows (pad 260)
  __shared__ __align__(16) float araw[8 * 260];   // raw pivot rows
  __shared__ float livef[256];
  __shared__ int   perm[256];
  __shared__ int   upbuf[256];
  __shared__ int   dnbuf[256];
  __shared__ int   wavecnt[8];
  __shared__ int   totinv;
  __shared__ float ldspad[10000];   // occupancy limiter: 1 block/CU

  const int tid = threadIdx.x;
  const int L   = tid & 63;       // lane
  const int w   = tid >> 6;       // wave

  const float* xrow = x + (size_t)blockIdx.x * NN;

  if ((int)blockIdx.x < 0) ((volatile float*)ldspad)[tid] = 1.0f;

  // ---- rank the +/-1 pattern: up = x>0 positions, dn = x<=0 positions
  bool pos = false;
  unsigned long long mask = 0;
  if (tid < NN) {
    float xv = xrow[tid];
    pos = xv > 0.0f;
    mask = __ballot(pos);
    if (L == 0) wavecnt[w] = __popcll(mask);
  }
  if (tid == 0) totinv = 0;
  if (tid < 256) livef[tid] = 1.0f;
  __syncthreads();
  if (tid < NN) {
    int base = 0;
    for (int i = 0; i < w; i++) base += wavecnt[i];
    int pbelow = __popcll(mask & ((1ull << L) - 1ull));
    if (pos) upbuf[base + pbelow] = tid;
    else     dnbuf[(64 * w - base) + (L - pbelow)] = tid;
  }
  __syncthreads();

  // ---- gather tile into vector registers: atK[m] = sub[L+64K][16w+m]
  f16v at0, at1, at2, at3;
  {
    i16v cg;
#pragma unroll
    for (int m = 0; m < 16; m++) cg[m] = dnbuf[16 * w + m];
#define GATHER_ROW(AT, K)                                                   \
    {                                                                       \
      const int rg = upbuf[L + 64 * (K)];                                   \
      _Pragma("unroll") for (int m = 0; m < 16; m++) {                      \
        const int c = cg[m];                                                \
        (AT)[m] = (c == rg) ? 0.0f                                          \
                            : F[(size_t)rg * NM1 + c - (c > rg ? 1 : 0)];   \
      }                                                                     \
    }
    GATHER_ROW(at0, 0) GATHER_ROW(at1, 1) GATHER_ROW(at2, 2) GATHER_ROW(at3, 3)
  }

  // ---- seed panel 0
  if (w == 0) {
#define SEED0_ROW(AT, K)                                                    \
    {                                                                       \
      const int rho = L + 64 * (K);                                         \
      _Pragma("unroll") for (int j = 0; j < 8; j++) PCT(rho, j) = (AT)[j];  \
    }
    SEED0_ROW(at0, 0) SEED0_ROW(at1, 1) SEED0_ROW(at2, 2) SEED0_ROW(at3, 3)
  }
  double det = 1.0;
  bool mylive = true;          // row-thread's own-row liveness (tid>=768)
  __syncthreads();

  // ---- panel loop
  for (int P = 0; P < 32; P++) {
    // row-threads cache their panel row in registers
    f8v pcrow;
    if (tid >= 768) {
      const int rr = tid - 768;
#pragma unroll
      for (int j = 0; j < 8; j++) pcrow[j] = PCT(rr, j);
    }

    i8v parr;
    // -------- 8 column-steps, ONE barrier each --------
#pragma unroll
    for (int s = 0; s < 8; s++) {
      // search: all threads, redundant; exclusion via register pivot history
      unsigned key = 0u;
#pragma unroll
      for (int k = 0; k < 4; k++) {
        int rho = L + 64 * k;
        float v = PCT(rho, s);
        bool excl = false;
#pragma unroll
        for (int q = 0; q < s; q++) excl |= (rho == parr[q]);
        unsigned b = __float_as_uint(fabsf(v)) & 0xFFFFFF00u;
        unsigned kq = excl ? 0u : (b | (unsigned)rho);
        key = key > kq ? key : kq;
      }
#pragma unroll
      for (int off = 32; off; off >>= 1) {
        unsigned o = (unsigned)__shfl_xor((int)key, off);
        key = key > o ? key : o;
      }
      const int p = (int)(key & 255u);
      parr[s] = p;
      const float piv = PCT(p, s);   // nobody writes col s this step
      det *= (double)piv;

      if (tid >= 768) {              // row-thread work
        const int rr = tid - 768;
        const float invp = 1.0f / piv;
        float l = (mylive && rr != p) ? pcrow[s] * invp : 0.0f;
        lbuf[s * 256 + rr] = l;
        if (rr == p) { mylive = false; livef[rr] = 0.0f; perm[P * 8 + s] = p; }
#pragma unroll
        for (int j = s + 1; j < 8; j++) {
          float uj = PCT(p, j);      // pivot row: benign same-value rewrite
          pcrow[j] = fmaf(-l, uj, pcrow[j]);
          PCT(rr, j) = pcrow[j];
        }
      }
      // raw pivot-row stash for the U-solve (live-col waves only)
      if ((2 * w + 1 > P) && L == (p & 63)) {
        const int kp = p >> 6;
#define STASH_ROW(AT, K)                                                    \
        if (kp == (K)) {                                                    \
          _Pragma("unroll") for (int q = 0; q < 4; q++)                     \
            *reinterpret_cast<float4*>(&araw[s * 260 + 16 * w + 4 * q]) =   \
                make_float4((AT)[4*q+0], (AT)[4*q+1],                       \
                            (AT)[4*q+2], (AT)[4*q+3]);                      \
        }
        STASH_ROW(at0, 0) STASH_ROW(at1, 1) STASH_ROW(at2, 2) STASH_ROW(at3, 3)
      }
      __syncthreads();
    }

    // -------- U-solve: U[t][j] = araw[t][j] - sum_{s<t} l_s[p_t]*U[s][j]
    if (tid < 256) {
      const int j = tid;
      f8v u;
#pragma unroll
      for (int t = 0; t < 8; t++) {
        int pt = perm[P * 8 + t];
        float acc = araw[t * 260 + j];
#pragma unroll
        for (int s2 = 0; s2 < t; s2++) acc = fmaf(-lbuf[s2 * 256 + pt], u[s2], acc);
        u[t] = acc;
        Ubuf[t * 260 + j] = acc;
      }
    }
    __syncthreads();

    // -------- rank-8 trailing update + seed next panel --------
    if (2 * w + 1 > P) {
#pragma unroll
      for (int t = 0; t < 8; t++) {
        const float lk0 = lbuf[t * 256 + L];
        const float lk1 = lbuf[t * 256 + L + 64];
        const float lk2 = lbuf[t * 256 + L + 128];
        const float lk3 = lbuf[t * 256 + L + 192];
#pragma unroll
        for (int q = 0; q < 4; q++) {
          const float4 u4 =
              *reinterpret_cast<const float4*>(&Ubuf[t * 260 + 16 * w + 4 * q]);
#define TU(AT, LK)                                                          \
          (AT)[4*q+0] = fmaf(-(LK), u4.x, (AT)[4*q+0]);                     \
          (AT)[4*q+1] = fmaf(-(LK), u4.y, (AT)[4*q+1]);                     \
          (AT)[4*q+2] = fmaf(-(LK), u4.z, (AT)[4*q+2]);                     \
          (AT)[4*q+3] = fmaf(-(LK), u4.w, (AT)[4*q+3]);
          TU(at0, lk0) TU(at1, lk1) TU(at2, lk2) TU(at3, lk3)
        }
      }
    }
    {
      const int wstar = (P + 1) >> 1, h = (P + 1) & 1;
      if (P < 31 && w == wstar) {
#define SEED_ROW(AT, K)                                                     \
        {                                                                   \
          const int rho = L + 64 * (K);                                     \
          const float lv = livef[rho];                                      \
          if (h == 0) {                                                     \
            _Pragma("unroll") for (int j = 0; j < 8; j++)                   \
              PCT(rho, j) = (AT)[j] * lv;                                   \
          } else {                                                          \
            _Pragma("unroll") for (int j = 0; j < 8; j++)                   \
              PCT(rho, j) = (AT)[8 + j] * lv;                               \
          }                                                                 \
        }
        SEED_ROW(at0, 0) SEED_ROW(at1, 1) SEED_ROW(at2, 2) SEED_ROW(at3, 3)
      }
    }
    __syncthreads();
  }

  // ---- permutation parity via parallel inversion count (verified in r2)
  int myinv = 0;
  {
    const int i0 = tid & 255;
    const int cbase = (tid >> 8) * 64;
    const int pi = perm[i0];
#pragma unroll 8
    for (int j = 0; j < 64; j++) {
      int jj = cbase + j;
      if (jj > i0 && perm[jj] < pi) myinv++;
    }
  }
#pragma unroll
  for (int off = 32; off; off >>= 1) myinv += __shfl_xor(myinv, off);
  if (L == 0) atomicAdd(&totinv, myinv);
  __syncthreads();
  if (tid == 0) out[blockIdx.x] = (float)((totinv & 1) ? -det : det);
}

extern "C" void kernel_launch(void* const* d_in, const int* in_sizes, int n_in,
                              void* d_out, int out_size, void* d_ws, size_t ws_size,
                              hipStream_t stream) {
  const float* x = (const float*)d_in[0];   // (1024, 512) fp32
  const float* F = (const float*)d_in[1];   // (512*512-512,) fp32
  float* out = (float*)d_out;               // (1024,) fp32
  const int B = out_size;                   // 1024
  hipLaunchKernelGGL(det_lu_kernel, dim3(B), dim3(1024), 0, stream, x, F, out);
}

// Round 6
// 2075.152 us; speedup vs baseline: 1.1728x; 1.1712x over previous
//
#include <hip/hip_runtime.h>

#define NN 512
#define NM1 511
#define PCT(r, j) pcT[(r) * 13 + (j)]

// X-macro helpers: T4x16(X) expands X(K,M) for K=0..3, M=0..15
#define T16(X, K) X(K,0) X(K,1) X(K,2) X(K,3) X(K,4) X(K,5) X(K,6) X(K,7) \
                  X(K,8) X(K,9) X(K,10) X(K,11) X(K,12) X(K,13) X(K,14) X(K,15)
#define T4x16(X) T16(X,0) T16(X,1) T16(X,2) T16(X,3)
#define T16S(X) X(0) X(1) X(2) X(3) X(4) X(5) X(6) X(7) \
                X(8) X(9) X(10) X(11) X(12) X(13) X(14) X(15)

// Ubuf quad -> component map for the trailing update
#define UU0 uq0.x
#define UU1 uq0.y
#define UU2 uq0.z
#define UU3 uq0.w
#define UU4 uq1.x
#define UU5 uq1.y
#define UU6 uq1.z
#define UU7 uq1.w
#define UU8 uq2.x
#define UU9 uq2.y
#define UU10 uq2.z
#define UU11 uq2.w
#define UU12 uq3.x
#define UU13 uq3.y
#define UU14 uq3.z
#define UU15 uq3.w

// One block per matrix (1024 blocks). Blocked LU, panel r=8, implicit partial
// pivoting. Thread tile: rows {L,L+64,L+128,L+192} x cols [16w,16w+16) held as
// 64 NAMED SCALAR floats aK_M (r5 post-mortem: 2-D arrays AND ext_vector
// lvalues both lowered through scratch; r2's constant-indexed scalars were the
// only no-spill codegen — named scalars are the strongest form of that class).
// Row-threads tid>=768 run the panel column-steps. r2's exact launch env.
__global__ __launch_bounds__(1024) void det_lu_kernel(
    const float* __restrict__ x,
    const float* __restrict__ F,
    float* __restrict__ out) {
  __shared__ __align__(16) float pcT[256 * 13];   // panel cols, row-major pad 13
  __shared__ __align__(16) float lbuf[8 * 256];   // multipliers per step
  __shared__ __align__(16) float Ubuf[8 * 260];   // final pivot rows (pad 260)
  __shared__ __align__(16) float araw[8 * 260];   // raw pivot rows
  __shared__ float livef[256];
  __shared__ int   perm[256];
  __shared__ int   upbuf[256];
  __shared__ int   dnbuf[256];
  __shared__ int   wavecnt[8];
  __shared__ int   totinv;

  const int tid = threadIdx.x;
  const int L   = tid & 63;       // lane
  const int w   = tid >> 6;       // wave

  const float* xrow = x + (size_t)blockIdx.x * NN;

  // ---- rank the +/-1 pattern: up = x>0 positions, dn = x<=0 positions
  bool pos = false;
  unsigned long long mask = 0;
  if (tid < NN) {
    float xv = xrow[tid];
    pos = xv > 0.0f;
    mask = __ballot(pos);
    if (L == 0) wavecnt[w] = __popcll(mask);
  }
  if (tid == 0) totinv = 0;
  if (tid < 256) livef[tid] = 1.0f;
  __syncthreads();
  if (tid < NN) {
    int base = 0;
    for (int i = 0; i < w; i++) base += wavecnt[i];
    int pbelow = __popcll(mask & ((1ull << L) - 1ull));
    if (pos) upbuf[base + pbelow] = tid;
    else     dnbuf[(64 * w - base) + (L - pbelow)] = tid;
  }
  __syncthreads();

  // ---- gather tile into 64 named scalars: aK_M = sub[L+64K][16w+M]
#define DECLC(M) const int cg##M = dnbuf[16 * w + (M)];
  T16S(DECLC)
  const int rg0 = upbuf[L];
  const int rg1 = upbuf[L + 64];
  const int rg2 = upbuf[L + 128];
  const int rg3 = upbuf[L + 192];
#define DECLA(K, M)                                                         \
  float a##K##_##M = (cg##M == rg##K)                                       \
      ? 0.0f                                                                \
      : F[(size_t)rg##K * NM1 + cg##M - (cg##M > rg##K ? 1 : 0)];
  T4x16(DECLA)

  // ---- seed panel 0: wave 0 writes PCT[row][0..7]
  if (w == 0) {
#define S0(K, M) if ((M) < 8) PCT(L + 64 * (K), (M)) = a##K##_##M;
    T4x16(S0)
  }
  double det = 1.0;
  bool mylive = true;          // row-thread's own-row liveness (tid>=768)
  __syncthreads();

  // ---- panel loop
  for (int P = 0; P < 32; P++) {
    // row-threads cache their panel row in registers
    float pcrow[8];
    if (tid >= 768) {
      const int rr = tid - 768;
#pragma unroll
      for (int j = 0; j < 8; j++) pcrow[j] = PCT(rr, j);
    }

    int parr[8];
    // -------- 8 column-steps, ONE barrier each --------
#pragma unroll
    for (int s = 0; s < 8; s++) {
      // search: all threads, redundant; exclusion via register pivot history
      unsigned key = 0u;
#pragma unroll
      for (int k = 0; k < 4; k++) {
        int rho = L + 64 * k;
        float v = PCT(rho, s);
        bool excl = false;
#pragma unroll
        for (int q = 0; q < s; q++) excl |= (rho == parr[q]);
        unsigned b = __float_as_uint(fabsf(v)) & 0xFFFFFF00u;
        unsigned kq = excl ? 0u : (b | (unsigned)rho);
        key = key > kq ? key : kq;
      }
#pragma unroll
      for (int off = 32; off; off >>= 1) {
        unsigned o = (unsigned)__shfl_xor((int)key, off);
        key = key > o ? key : o;
      }
      const int p = (int)(key & 255u);
      parr[s] = p;
      const float piv = PCT(p, s);   // nobody writes col s this step
      det *= (double)piv;

      if (tid >= 768) {              // row-thread work
        const int rr = tid - 768;
        const float invp = 1.0f / piv;
        float l = (mylive && rr != p) ? pcrow[s] * invp : 0.0f;
        lbuf[s * 256 + rr] = l;
        if (rr == p) { mylive = false; livef[rr] = 0.0f; perm[P * 8 + s] = p; }
#pragma unroll
        for (int j = s + 1; j < 8; j++) {
          float uj = PCT(p, j);      // pivot row: benign same-value rewrite
          pcrow[j] = fmaf(-l, uj, pcrow[j]);
          PCT(rr, j) = pcrow[j];
        }
      }
      // raw pivot-row stash for the U-solve (live-col waves only)
      if ((2 * w + 1 > P) && L == (p & 63)) {
        const int kp = p >> 6;
        const int sb = s * 260 + 16 * w;
#define ST(K, M) if (kp == (K)) araw[sb + (M)] = a##K##_##M;
        T4x16(ST)
      }
      __syncthreads();
    }

    // -------- U-solve: U[t][j] = araw[t][j] - sum_{s<t} l_s[p_t]*U[s][j]
    if (tid < 256) {
      const int j = tid;
      float u[8];
#pragma unroll
      for (int t = 0; t < 8; t++) {
        int pt = perm[P * 8 + t];
        float acc = araw[t * 260 + j];
#pragma unroll
        for (int s2 = 0; s2 < t; s2++) acc = fmaf(-lbuf[s2 * 256 + pt], u[s2], acc);
        u[t] = acc;
        Ubuf[t * 260 + j] = acc;
      }
    }
    __syncthreads();

    // -------- rank-8 trailing update + seed next panel --------
    if (2 * w + 1 > P) {
      for (int t = 0; t < 8; t++) {
        const float lk0 = lbuf[t * 256 + L];
        const float lk1 = lbuf[t * 256 + L + 64];
        const float lk2 = lbuf[t * 256 + L + 128];
        const float lk3 = lbuf[t * 256 + L + 192];
        const float4 uq0 = *reinterpret_cast<const float4*>(&Ubuf[t * 260 + 16 * w + 0]);
        const float4 uq1 = *reinterpret_cast<const float4*>(&Ubuf[t * 260 + 16 * w + 4]);
        const float4 uq2 = *reinterpret_cast<const float4*>(&Ubuf[t * 260 + 16 * w + 8]);
        const float4 uq3 = *reinterpret_cast<const float4*>(&Ubuf[t * 260 + 16 * w + 12]);
#define TUE(K, M) a##K##_##M = fmaf(-lk##K, UU##M, a##K##_##M);
        T4x16(TUE)
      }
    }
    {
      const int wstar = (P + 1) >> 1, h = (P + 1) & 1;
      if (P < 31 && w == wstar) {
        const float lv0 = livef[L];
        const float lv1 = livef[L + 64];
        const float lv2 = livef[L + 128];
        const float lv3 = livef[L + 192];
        if (h == 0) {
#define SE0(K, M) if ((M) < 8) PCT(L + 64 * (K), (M)) = a##K##_##M * lv##K;
          T4x16(SE0)
        } else {
#define SE1(K, M) if ((M) >= 8) PCT(L + 64 * (K), (M) - 8) = a##K##_##M * lv##K;
          T4x16(SE1)
        }
      }
    }
    __syncthreads();
  }

  // ---- permutation parity via parallel inversion count (verified in r2)
  int myinv = 0;
  {
    const int i0 = tid & 255;
    const int cbase = (tid >> 8) * 64;
    const int pi = perm[i0];
#pragma unroll 8
    for (int j = 0; j < 64; j++) {
      int jj = cbase + j;
      if (jj > i0 && perm[jj] < pi) myinv++;
    }
  }
#pragma unroll
  for (int off = 32; off; off >>= 1) myinv += __shfl_xor(myinv, off);
  if (L == 0) atomicAdd(&totinv, myinv);
  __syncthreads();
  if (tid == 0) out[blockIdx.x] = (float)((totinv & 1) ? -det : det);
}

extern "C" void kernel_launch(void* const* d_in, const int* in_sizes, int n_in,
                              void* d_out, int out_size, void* d_ws, size_t ws_size,
                              hipStream_t stream) {
  const float* x = (const float*)d_in[0];   // (1024, 512) fp32
  const float* F = (const float*)d_in[1];   // (512*512-512,) fp32
  float* out = (float*)d_out;               // (1024,) fp32
  const int B = out_size;                   // 1024
  hipLaunchKernelGGL(det_lu_kernel, dim3(B), dim3(1024), 0, stream, x, F, out);
}